// Round 1
// baseline (3512.505 us; speedup 1.0000x reference)
//
#include <hip/hip_runtime.h>
#include <hip/hip_bf16.h>

typedef unsigned short u16;
typedef _Float16 f16;
typedef _Float16 f16x8 __attribute__((ext_vector_type(8)));
typedef short s8v __attribute__((ext_vector_type(8)));
typedef float f4v __attribute__((ext_vector_type(4)));

// LSTM LDS layout: 128 weight frags (kt 6,7) + pre staging + h state
#define LSTM_WLDS 131072                 // 128 frags x 64 lanes x 16 B
#define LSTM_PLDS 4096                   // plds[2][1024] f16
#define LSTM_HLDS 1024                   // hl[2][256] f16
#define LSTM_SMEM (LSTM_WLDS + LSTM_PLDS + LSTM_HLDS)   // 136192

__device__ __forceinline__ u16 f2bf(float f) {
    union { float f; unsigned u; } v; v.f = f;
    unsigned r = v.u + 0x7FFF + ((v.u >> 16) & 1);
    return (u16)(r >> 16);
}
__device__ __forceinline__ u16 f2h(float f) {
    f16 h = (f16)f;
    union { f16 h; u16 u; } v; v.h = h;
    return v.u;
}
__device__ __forceinline__ float sigm(float x) { return 1.f / (1.f + __expf(-x)); }
__device__ __forceinline__ float fast_tanh(float x) {
    float ax = fabsf(x);
    float e = __expf(2.f * ax);
    float r = 1.f - 2.f / (e + 1.f);   // overflow-safe: e=inf -> r=1
    return copysignf(r, x);
}

// ---------------------------------------------------------------------------
// Weight prep: transposes to [N][K] bf16 for MFMA B-operand for the GEMMs,
// and packs Ul into f16 MFMA B-fragment layout for the LSTM:
//   512 frags, frag F: tile = (w,cg,g), kt;  lane l holds 8 f16:
//     B[k][n], k = kt*32 + (l>>4)*8 + j,  n = g*256 + w*64 + cg*16 + (l&15)
//   F < 384: register region, F = tile*6 + kt (kt 0..5)
//   F >=384: LDS region,      F = 384 + tile*2 + (kt-6)
// ---------------------------------------------------------------------------
__global__ __launch_bounds__(256) void prep_kernel(
    const float* __restrict__ Wx, const float* __restrict__ Wc,
    const float* __restrict__ Wl, const float* __restrict__ Wo,
    const float* __restrict__ Ul,
    u16* __restrict__ wxT, u16* __restrict__ wcT, u16* __restrict__ wlT,
    u16* __restrict__ woT, u16* __restrict__ ulB)
{
    int i = blockIdx.x * 256 + threadIdx.x;
    if (i < 65536) {                    // WxT[n][k] : 128x512
        int n = i >> 9, k = i & 511;
        wxT[i] = f2bf(Wx[k * 128 + n]);
    } else if (i < 131072) {            // WcT
        int t = i - 65536;
        int n = t >> 9, k = t & 511;
        wcT[t] = f2bf(Wc[k * 128 + n]);
    } else if (i < 425984) {            // WlT[n][k] : 1024x288 (K padded 257->288)
        int t = i - 131072;
        int n = t / 288, k = t % 288;
        wlT[t] = (k < 257) ? f2bf(Wl[k * 1024 + n]) : (u16)0;
    } else if (i < 491520) {            // WoT[n][k] : 256x256
        int t = i - 425984;
        int n = t >> 8, k = t & 255;
        woT[t] = f2bf(Wo[k * 256 + n]);
    } else {                            // ulB: 512 B-frags f16, i in [491520, 524288)
        int e = i - 491520;             // [0, 32768): one f16x8 element each
        int F = e >> 6, lane = e & 63;
        int m16 = lane & 15, quad = lane >> 4;
        int tile, kt;
        if (F < 384) { tile = F / 6; kt = F - tile * 6; }
        else { int L = F - 384; tile = L >> 1; kt = 6 + (L & 1); }
        int wv = tile >> 4, cg = (tile >> 2) & 3, g = tile & 3;
        int n = g * 256 + wv * 64 + cg * 16 + m16;
        int k0 = kt * 32 + quad * 8;
        u16* o = ulB + (size_t)e * 8;
        #pragma unroll
        for (int jj = 0; jj < 8; ++jj)
            o[jj] = f2h(Ul[(size_t)(k0 + jj) * 1024 + n]);
    }
}

// ---------------------------------------------------------------------------
// s[b,t] = sum_k x[b,t,k]   (one wave per row)
// ---------------------------------------------------------------------------
__global__ __launch_bounds__(256) void row_sums(const float4* __restrict__ x4,
                                                float* __restrict__ s)
{
    int w = threadIdx.x >> 6, lane = threadIdx.x & 63;
    size_t row = (size_t)blockIdx.x * 4 + w;
    const float4* r = x4 + row * 128;
    float4 a = r[lane], b = r[64 + lane];
    float sum = a.x + a.y + a.z + a.w + b.x + b.y + b.z + b.w;
    #pragma unroll
    for (int d = 32; d >= 1; d >>= 1) sum += __shfl_xor(sum, d);
    if (lane == 0) s[row] = sum;
}

// ---------------------------------------------------------------------------
// Count recurrence, 3-phase chunked (8 chunks of 128 steps per batch):
// A: per-chunk zero-init scan -> cend, P=prod(s).  B: combine chunk heads.
// C: re-scan with true c_in, write bf16 x and log1p(count).
// ---------------------------------------------------------------------------
__global__ __launch_bounds__(512) void count_phaseA(const float* __restrict__ x,
                                                    const float* __restrict__ s,
                                                    float* __restrict__ cend,
                                                    float* __restrict__ Pq)
{
    int k = threadIdx.x, bi = blockIdx.x;
    int b = bi >> 3, qc = bi & 7;
    const float* xb = x + ((size_t)b * 1024 + qc * 128) * 512;
    const float* sb = s + b * 1024 + qc * 128;
    float c = 0.f, P = 1.f;
    for (int t0 = 0; t0 < 128; t0 += 8) {
        float xv[8], sv[8];
        #pragma unroll
        for (int i = 0; i < 8; ++i) {
            xv[i] = xb[(size_t)(t0 + i) * 512 + k];
            sv[i] = sb[t0 + i];
        }
        #pragma unroll
        for (int i = 0; i < 8; ++i) { c = sv[i] * c + xv[i]; P *= sv[i]; }
    }
    cend[(size_t)bi * 512 + k] = c;
    if (k == 0) Pq[bi] = P;
}

__global__ __launch_bounds__(512) void count_phaseB(const float* __restrict__ cend,
                                                    const float* __restrict__ Pq,
                                                    float* __restrict__ cin)
{
    int k = threadIdx.x, b = blockIdx.x;
    float c = 0.f;
    for (int q = 0; q < 8; ++q) {
        int bi = b * 8 + q;
        cin[(size_t)bi * 512 + k] = c;
        c = Pq[bi] * c + cend[(size_t)bi * 512 + k];
    }
}

__global__ __launch_bounds__(512) void count_phaseC(const float* __restrict__ x,
                                                    const float* __restrict__ s,
                                                    const float* __restrict__ cin,
                                                    u16* __restrict__ xbf,
                                                    u16* __restrict__ clog)
{
    int k = threadIdx.x, bi = blockIdx.x;
    int b = bi >> 3, qc = bi & 7;
    size_t base = ((size_t)b * 1024 + qc * 128) * 512;
    const float* xb = x + base;
    const float* sb = s + b * 1024 + qc * 128;
    u16* xo = xbf + base;
    u16* co = clog + base;
    float c = cin[(size_t)bi * 512 + k];
    for (int t0 = 0; t0 < 128; t0 += 8) {
        float xv[8], sv[8];
        #pragma unroll
        for (int i = 0; i < 8; ++i) {
            xv[i] = xb[(size_t)(t0 + i) * 512 + k];
            sv[i] = sb[t0 + i];
        }
        #pragma unroll
        for (int i = 0; i < 8; ++i) {
            c = sv[i] * c + xv[i];
            size_t idx = (size_t)(t0 + i) * 512 + k;
            xo[idx] = f2bf(xv[i]);
            co[idx] = f2bf(log1pf(c));
        }
    }
}

// ---------------------------------------------------------------------------
// xc[:,256] = exp(-(delta*Wd+bd)); xc[:,257:288] = 0
// ---------------------------------------------------------------------------
__global__ __launch_bounds__(256) void fill_xc(const float* __restrict__ delta,
                                               const float* __restrict__ Wd,
                                               const float* __restrict__ bd,
                                               u16* __restrict__ xc)
{
    int i = blockIdx.x * 256 + threadIdx.x;   // 65536*32
    int row = i >> 5, cc = i & 31;
    float v = 0.f;
    if (cc == 0) v = __expf(-(delta[row] * Wd[0] + bd[0]));
    xc[(size_t)row * 288 + 256 + cc] = f2bf(v);
}

// ---------------------------------------------------------------------------
// Generic 128x128-tile bf16 MFMA GEMM: C[row, colofs+col] = A@B + bias.
// ---------------------------------------------------------------------------
template <int EPI>
__global__ __launch_bounds__(256) void gemm128(const u16* __restrict__ A,
                                               const u16* __restrict__ BT,
                                               const float* __restrict__ bias,
                                               u16* __restrict__ C,
                                               int K, int ldc, int colofs)
{
    __shared__ u16 Alds[128 * 40];
    __shared__ u16 Blds[128 * 40];
    int tid = threadIdx.x;
    int m0 = blockIdx.x * 128, n0 = blockIdx.y * 128;
    int lane = tid & 63, w = tid >> 6, quad = lane >> 4, m16 = lane & 15;
    int wm = w & 1, wn = w >> 1;
    f4v acc[4][4];
    #pragma unroll
    for (int i = 0; i < 4; ++i)
        #pragma unroll
        for (int j = 0; j < 4; ++j) acc[i][j] = (f4v){0.f, 0.f, 0.f, 0.f};

    for (int k0 = 0; k0 < K; k0 += 32) {
        #pragma unroll
        for (int p = 0; p < 2; ++p) {
            int e = (p * 256 + tid) * 8;
            int r = e >> 5, cc = e & 31;
            *(uint4*)&Alds[r * 40 + cc] =
                *(const uint4*)&A[(size_t)(m0 + r) * K + k0 + cc];
            *(uint4*)&Blds[r * 40 + cc] =
                *(const uint4*)&BT[(size_t)(n0 + r) * K + k0 + cc];
        }
        __syncthreads();
        s8v af[4], bf[4];
        #pragma unroll
        for (int i = 0; i < 4; ++i)
            af[i] = *(const s8v*)&Alds[(wm * 64 + i * 16 + m16) * 40 + quad * 8];
        #pragma unroll
        for (int i = 0; i < 4; ++i)
            bf[i] = *(const s8v*)&Blds[(wn * 64 + i * 16 + m16) * 40 + quad * 8];
        #pragma unroll
        for (int i = 0; i < 4; ++i)
            #pragma unroll
            for (int nj = 0; nj < 4; ++nj)
                acc[i][nj] = __builtin_amdgcn_mfma_f32_16x16x32_bf16(
                    af[i], bf[nj], acc[i][nj], 0, 0, 0);
        __syncthreads();
    }
    #pragma unroll
    for (int nj = 0; nj < 4; ++nj) {
        int col = n0 + wn * 64 + nj * 16 + m16;
        float bv = bias[col];
        #pragma unroll
        for (int i = 0; i < 4; ++i)
            #pragma unroll
            for (int r = 0; r < 4; ++r) {
                int row = m0 + wm * 64 + i * 16 + quad * 4 + r;
                float v = acc[i][nj][r] + bv;
                C[(size_t)row * ldc + colofs + col] = (EPI == 0) ? f2bf(v) : f2h(v);
            }
    }
}

// ---------------------------------------------------------------------------
// LSTM over T=1024 via broadcast-A MFMA GEMV. One block per batch, 256 thr.
// Wave w owns h-cols [w*64, w*64+64) = 4 clusters (cg) of 16 cols x 4 gates.
// A-frag = h broadcast into all 16 rows (all lanes read the same quad k-slice
// from LDS) -> every row of D equals z, so acc[g][0] on every lane is
// z[col = w*64+cg*16+m16]; gates are computed redundantly per quad with no
// cross-lane traffic; lane stores exactly column tid (select by quad).
// Ul resident as B-frags: kt 0..5 in regs (384/wave, VGPR+AGPR unified),
// kt 6..7 in LDS (128 KB). pre[t] staged via LDS double buffer.
// ---------------------------------------------------------------------------
__global__ __launch_bounds__(256, 1) void lstm_kernel(const f16* __restrict__ pre,
                                                      const u16* __restrict__ ulB,
                                                      u16* __restrict__ hout)
{
    extern __shared__ char smem[];
    f16x8* wlds = (f16x8*)smem;                         // [128][64] frags kt 6,7
    f16* plds = (f16*)(smem + LSTM_WLDS);               // [2][1024] pre staging
    f16* hl   = (f16*)(smem + LSTM_WLDS + LSTM_PLDS);   // [2][256] h state
    const int tid = threadIdx.x, b = blockIdx.x;
    const int w = tid >> 6, lane = tid & 63, quad = lane >> 4, m16 = lane & 15;

    const f16x8* ub = (const f16x8*)ulB;
    // register-resident weights: kt 0..5 for this wave's 16 (cg,g) tiles
    f16x8 wr[4][4][6];
    #pragma unroll
    for (int cg = 0; cg < 4; ++cg)
        #pragma unroll
        for (int g = 0; g < 4; ++g)
            #pragma unroll
            for (int kt = 0; kt < 6; ++kt)
                wr[cg][g][kt] =
                    ub[(size_t)(((w * 16 + cg * 4 + g) * 6 + kt) * 64 + lane)];
    // stage LDS-resident weights (own wave's 32 frags; only read by this wave)
    {
        const f16x8* ubl = ub + 384 * 64;
        #pragma unroll
        for (int i2 = 0; i2 < 32; ++i2)
            wlds[(w * 32 + i2) * 64 + lane] = ubl[(size_t)((w * 32 + i2) * 64 + lane)];
    }
    const f16* prep_ = pre + (size_t)b * 1024 * 1024;
    u16* ho = hout + (size_t)b * 1024 * 256;
    {
        uint2 p0 = *(const uint2*)&prep_[tid * 4];      // pre[t=0] -> plds[0]
        *(uint2*)&plds[tid * 4] = p0;
        hl[tid] = (f16)0.f;
    }
    float c[4] = {0.f, 0.f, 0.f, 0.f};
    __syncthreads();

    const f4v z4 = {0.f, 0.f, 0.f, 0.f};
    const int wldsbase = w * 32 * 64 + lane;
    #pragma unroll 1
    for (int t = 0; t < 1024; ++t) {
        int t1 = (t < 1023) ? (t + 1) : 1023;
        uint2 pv = *(const uint2*)&prep_[(size_t)t1 * 1024 + tid * 4];  // prefetch
        const int cb = (t & 1) * 256 + quad * 8;
        const int pb = (t & 1) * 1024 + w * 64 + m16;
        f16x8 av[8];                                    // h k-slices, broadcast
        #pragma unroll
        for (int kt = 0; kt < 8; ++kt)
            av[kt] = *(const f16x8*)&hl[cb + kt * 32];
        float hv[4];
        #pragma unroll
        for (int cg = 0; cg < 4; ++cg) {
            f16x8 wl[4][2];
            #pragma unroll
            for (int g = 0; g < 4; ++g)
                #pragma unroll
                for (int k6 = 0; k6 < 2; ++k6)
                    wl[g][k6] = wlds[wldsbase + ((cg * 4 + g) * 2 + k6) * 64];
            f4v acc[4];
            #pragma unroll
            for (int g = 0; g < 4; ++g)
                acc[g] = __builtin_amdgcn_mfma_f32_16x16x32_f16(
                    av[0], wr[cg][g][0], z4, 0, 0, 0);
            #pragma unroll
            for (int kt = 1; kt < 6; ++kt)
                #pragma unroll
                for (int g = 0; g < 4; ++g)
                    acc[g] = __builtin_amdgcn_mfma_f32_16x16x32_f16(
                        av[kt], wr[cg][g][kt], acc[g], 0, 0, 0);
            #pragma unroll
            for (int k6 = 0; k6 < 2; ++k6)
                #pragma unroll
                for (int g = 0; g < 4; ++g)
                    acc[g] = __builtin_amdgcn_mfma_f32_16x16x32_f16(
                        av[6 + k6], wl[g][k6], acc[g], 0, 0, 0);
            float z0 = acc[0][0] + (float)plds[pb + cg * 16];           // i
            float z1 = acc[1][0] + (float)plds[pb + 256 + cg * 16];     // f
            float z2 = acc[2][0] + (float)plds[pb + 512 + cg * 16];     // g
            float z3 = acc[3][0] + (float)plds[pb + 768 + cg * 16];     // o
            float ig = sigm(z0), fg = sigm(z1);
            float gg = fast_tanh(z2), og = sigm(z3);
            c[cg] = fg * c[cg] + ig * gg;
            hv[cg] = og * fast_tanh(c[cg]);
        }
        // lane's column is exactly tid: col = w*64 + quad*16 + m16
        float hs = (quad == 0) ? hv[0] : (quad == 1) ? hv[1]
                 : (quad == 2) ? hv[2] : hv[3];
        hl[((t + 1) & 1) * 256 + tid] = (f16)hs;
        ho[(size_t)t * 256 + tid] = f2bf(hs);
        *(uint2*)&plds[((t + 1) & 1) * 1024 + tid * 4] = pv;
        __syncthreads();
    }
}

// ---------------------------------------------------------------------------
// out[row] = sum_n sigmoid(h[row]@Wo[:,n] + bo[n]) * q[row,n]
// ---------------------------------------------------------------------------
__global__ __launch_bounds__(256) void gemm_out(const u16* __restrict__ H,
                                                const u16* __restrict__ woT,
                                                const float* __restrict__ bo,
                                                const float* __restrict__ q,
                                                float* __restrict__ out)
{
    __shared__ u16 Alds[64 * 40];
    __shared__ u16 Blds[256 * 40];
    __shared__ float red[64][4];
    int tid = threadIdx.x;
    int m0 = blockIdx.x * 64;
    int lane = tid & 63, w = tid >> 6, quad = lane >> 4, m16 = lane & 15;
    f4v acc[4][4];
    #pragma unroll
    for (int i = 0; i < 4; ++i)
        #pragma unroll
        for (int j = 0; j < 4; ++j) acc[i][j] = (f4v){0.f, 0.f, 0.f, 0.f};

    for (int k0 = 0; k0 < 256; k0 += 32) {
        {
            int e = tid * 8;
            int r = e >> 5, cc = e & 31;
            *(uint4*)&Alds[r * 40 + cc] =
                *(const uint4*)&H[(size_t)(m0 + r) * 256 + k0 + cc];
        }
        #pragma unroll
        for (int p = 0; p < 4; ++p) {
            int e = (p * 256 + tid) * 8;
            int r = e >> 5, cc = e & 31;
            *(uint4*)&Blds[r * 40 + cc] =
                *(const uint4*)&woT[(size_t)r * 256 + k0 + cc];
        }
        __syncthreads();
        s8v af[4], bf[4];
        #pragma unroll
        for (int i = 0; i < 4; ++i)
            af[i] = *(const s8v*)&Alds[(i * 16 + m16) * 40 + quad * 8];
        #pragma unroll
        for (int i = 0; i < 4; ++i)
            bf[i] = *(const s8v*)&Blds[(w * 64 + i * 16 + m16) * 40 + quad * 8];
        #pragma unroll
        for (int i = 0; i < 4; ++i)
            #pragma unroll
            for (int nj = 0; nj < 4; ++nj)
                acc[i][nj] = __builtin_amdgcn_mfma_f32_16x16x32_bf16(
                    af[i], bf[nj], acc[i][nj], 0, 0, 0);
        __syncthreads();
    }
    float rsum[4][4];
    #pragma unroll
    for (int i = 0; i < 4; ++i)
        #pragma unroll
        for (int r = 0; r < 4; ++r) rsum[i][r] = 0.f;
    #pragma unroll
    for (int nj = 0; nj < 4; ++nj) {
        int col = w * 64 + nj * 16 + m16;
        float bv = bo[col];
        #pragma unroll
        for (int i = 0; i < 4; ++i)
            #pragma unroll
            for (int r = 0; r < 4; ++r) {
                int row = m0 + i * 16 + quad * 4 + r;
                float v = sigm(acc[i][nj][r] + bv);
                rsum[i][r] += v * q[(size_t)row * 256 + col];
            }
    }
    #pragma unroll
    for (int d = 1; d <= 8; d <<= 1)
        #pragma unroll
        for (int i = 0; i < 4; ++i)
            #pragma unroll
            for (int r = 0; r < 4; ++r) rsum[i][r] += __shfl_xor(rsum[i][r], d);
    if (m16 == 0) {
        #pragma unroll
        for (int i = 0; i < 4; ++i)
            #pragma unroll
            for (int r = 0; r < 4; ++r)
                red[i * 16 + quad * 4 + r][w] = rsum[i][r];
    }
    __syncthreads();
    if (tid < 64)
        out[m0 + tid] = red[tid][0] + red[tid][1] + red[tid][2] + red[tid][3];
}

// ---------------------------------------------------------------------------
extern "C" void kernel_launch(void* const* d_in, const int* in_sizes, int n_in,
                              void* d_out, int out_size, void* d_ws, size_t ws_size,
                              hipStream_t stream)
{
    (void)in_sizes; (void)n_in; (void)out_size; (void)ws_size;
    const float* x     = (const float*)d_in[0];
    const float* delta = (const float*)d_in[1];
    const float* q     = (const float*)d_in[2];
    const float* Wx    = (const float*)d_in[3];
    const float* bx    = (const float*)d_in[4];
    const float* Wc    = (const float*)d_in[5];
    const float* bc    = (const float*)d_in[6];
    const float* Wd    = (const float*)d_in[7];
    const float* bd    = (const float*)d_in[8];
    const float* Wl    = (const float*)d_in[9];
    const float* Ul    = (const float*)d_in[10];
    const float* bl    = (const float*)d_in[11];
    const float* Wo    = (const float*)d_in[12];
    const float* bo    = (const float*)d_in[13];

    char* ws = (char*)d_ws;
    float* s_buf = (float*)(ws + 0);            // 256 KB
    u16* ulB     = (u16*)(ws + 262144);         // 512 KB (B-frag layout f16)
    u16* wxT     = (u16*)(ws + 786432);         // 128 KB
    u16* wcT     = (u16*)(ws + 917504);         // 128 KB
    u16* wlT     = (u16*)(ws + 1048576);        // 576 KB
    u16* woT     = (u16*)(ws + 1638400);        // 128 KB
    u16* xc      = (u16*)(ws + 1769472);        // 36 MB  [65536 x 288] bf16
    u16* hbuf    = (u16*)(ws + 39518208);       // 32 MB  [65536 x 256] bf16
    u16* xbf     = (u16*)(ws + 73072640);       // 64 MB  bf16 copy of x
    u16* clog    = (u16*)(ws + 140181504);      // 64 MB  log1p(counts) bf16
    f16* pre     = (f16*)(ws + 73072640);       // 128 MB f16, aliases xbf+clog
    // count-scan scratch lives in the (not yet used) hbuf region
    float* cend  = (float*)hbuf;                // 1 MB
    float* cin   = (float*)(ws + 39518208 + (1 << 20));   // 1 MB
    float* Pq    = (float*)(ws + 39518208 + (2 << 20));   // 2 KB

    // allow >64KB dynamic LDS for the LSTM kernel (gfx950: 160 KB/WG)
    hipFuncSetAttribute((const void*)lstm_kernel,
                        hipFuncAttributeMaxDynamicSharedMemorySize, LSTM_SMEM);

    prep_kernel<<<2048, 256, 0, stream>>>(Wx, Wc, Wl, Wo, Ul, wxT, wcT, wlT, woT, ulB);
    row_sums<<<16384, 256, 0, stream>>>((const float4*)x, s_buf);
    count_phaseA<<<512, 512, 0, stream>>>(x, s_buf, cend, Pq);
    count_phaseB<<<64, 512, 0, stream>>>(cend, Pq, cin);
    count_phaseC<<<512, 512, 0, stream>>>(x, s_buf, cin, xbf, clog);
    fill_xc<<<8192, 256, 0, stream>>>(delta, Wd, bd, xc);
    gemm128<0><<<dim3(512, 1), 256, 0, stream>>>(xbf, wxT, bx, xc, 512, 288, 0);
    gemm128<0><<<dim3(512, 1), 256, 0, stream>>>(clog, wcT, bc, xc, 512, 288, 128);
    gemm128<1><<<dim3(512, 8), 256, 0, stream>>>(xc, wlT, bl, (u16*)pre, 288, 1024, 0);
    lstm_kernel<<<64, 256, LSTM_SMEM, stream>>>(pre, ulB, hbuf);
    gemm_out<<<1024, 256, 0, stream>>>(hbuf, woT, bo, q, (float*)d_out);
}

// Round 2
// 2864.987 us; speedup vs baseline: 1.2260x; 1.2260x over previous
//
#include <hip/hip_runtime.h>
#include <hip/hip_bf16.h>

typedef unsigned short u16;
typedef _Float16 f16;
typedef _Float16 f16x8 __attribute__((ext_vector_type(8)));
typedef short s8v __attribute__((ext_vector_type(8)));
typedef float f4v __attribute__((ext_vector_type(4)));

// LSTM LDS layout: 128 weight frags (kt 6,7) + h state double buffer
#define LSTM_WLDS 131072                 // 128 frags x 64 lanes x 16 B
#define LSTM_HLDS 1024                   // hl[2][256] f16
#define LSTM_SMEM (LSTM_WLDS + LSTM_HLDS)   // 132096

__device__ __forceinline__ u16 f2bf(float f) {
    union { float f; unsigned u; } v; v.f = f;
    unsigned r = v.u + 0x7FFF + ((v.u >> 16) & 1);
    return (u16)(r >> 16);
}
__device__ __forceinline__ u16 f2h(float f) {
    f16 h = (f16)f;
    union { f16 h; u16 u; } v; v.h = h;
    return v.u;
}
__device__ __forceinline__ float sigm(float x) { return 1.f / (1.f + __expf(-x)); }
__device__ __forceinline__ float fast_tanh(float x) {
    float ax = fabsf(x);
    float e = __expf(2.f * ax);
    float r = 1.f - 2.f / (e + 1.f);   // overflow-safe: e=inf -> r=1
    return copysignf(r, x);
}

// ---------------------------------------------------------------------------
// Weight prep: transposes to [N][K] bf16 for MFMA B-operand for the GEMMs,
// and packs Ul into f16 MFMA B-fragment layout for the LSTM:
//   512 frags, frag F: tile = (w,cg,g), kt;  lane l holds 8 f16:
//     B[k][n], k = kt*32 + (l>>4)*8 + j,  n = g*256 + w*64 + cg*16 + (l&15)
//   F < 384: register region, F = tile*6 + kt (kt 0..5)
//   F >=384: LDS region,      F = 384 + tile*2 + (kt-6)
// ---------------------------------------------------------------------------
__global__ __launch_bounds__(256) void prep_kernel(
    const float* __restrict__ Wx, const float* __restrict__ Wc,
    const float* __restrict__ Wl, const float* __restrict__ Wo,
    const float* __restrict__ Ul,
    u16* __restrict__ wxT, u16* __restrict__ wcT, u16* __restrict__ wlT,
    u16* __restrict__ woT, u16* __restrict__ ulB)
{
    int i = blockIdx.x * 256 + threadIdx.x;
    if (i < 65536) {                    // WxT[n][k] : 128x512
        int n = i >> 9, k = i & 511;
        wxT[i] = f2bf(Wx[k * 128 + n]);
    } else if (i < 131072) {            // WcT
        int t = i - 65536;
        int n = t >> 9, k = t & 511;
        wcT[t] = f2bf(Wc[k * 128 + n]);
    } else if (i < 425984) {            // WlT[n][k] : 1024x288 (K padded 257->288)
        int t = i - 131072;
        int n = t / 288, k = t % 288;
        wlT[t] = (k < 257) ? f2bf(Wl[k * 1024 + n]) : (u16)0;
    } else if (i < 491520) {            // WoT[n][k] : 256x256
        int t = i - 425984;
        int n = t >> 8, k = t & 255;
        woT[t] = f2bf(Wo[k * 256 + n]);
    } else {                            // ulB: 512 B-frags f16, i in [491520, 524288)
        int e = i - 491520;             // [0, 32768): one f16x8 element each
        int F = e >> 6, lane = e & 63;
        int m16 = lane & 15, quad = lane >> 4;
        int tile, kt;
        if (F < 384) { tile = F / 6; kt = F - tile * 6; }
        else { int L = F - 384; tile = L >> 1; kt = 6 + (L & 1); }
        int wv = tile >> 4, cg = (tile >> 2) & 3, g = tile & 3;
        int n = g * 256 + wv * 64 + cg * 16 + m16;
        int k0 = kt * 32 + quad * 8;
        u16* o = ulB + (size_t)e * 8;
        #pragma unroll
        for (int jj = 0; jj < 8; ++jj)
            o[jj] = f2h(Ul[(size_t)(k0 + jj) * 1024 + n]);
    }
}

// ---------------------------------------------------------------------------
// s[b,t] = sum_k x[b,t,k]   (one wave per row)
// ---------------------------------------------------------------------------
__global__ __launch_bounds__(256) void row_sums(const float4* __restrict__ x4,
                                                float* __restrict__ s)
{
    int w = threadIdx.x >> 6, lane = threadIdx.x & 63;
    size_t row = (size_t)blockIdx.x * 4 + w;
    const float4* r = x4 + row * 128;
    float4 a = r[lane], b = r[64 + lane];
    float sum = a.x + a.y + a.z + a.w + b.x + b.y + b.z + b.w;
    #pragma unroll
    for (int d = 32; d >= 1; d >>= 1) sum += __shfl_xor(sum, d);
    if (lane == 0) s[row] = sum;
}

// ---------------------------------------------------------------------------
// Count recurrence, 3-phase chunked (8 chunks of 128 steps per batch):
// A: per-chunk zero-init scan -> cend, P=prod(s).  B: combine chunk heads.
// C: re-scan with true c_in, write bf16 x and log1p(count).
// ---------------------------------------------------------------------------
__global__ __launch_bounds__(512) void count_phaseA(const float* __restrict__ x,
                                                    const float* __restrict__ s,
                                                    float* __restrict__ cend,
                                                    float* __restrict__ Pq)
{
    int k = threadIdx.x, bi = blockIdx.x;
    int b = bi >> 3, qc = bi & 7;
    const float* xb = x + ((size_t)b * 1024 + qc * 128) * 512;
    const float* sb = s + b * 1024 + qc * 128;
    float c = 0.f, P = 1.f;
    for (int t0 = 0; t0 < 128; t0 += 8) {
        float xv[8], sv[8];
        #pragma unroll
        for (int i = 0; i < 8; ++i) {
            xv[i] = xb[(size_t)(t0 + i) * 512 + k];
            sv[i] = sb[t0 + i];
        }
        #pragma unroll
        for (int i = 0; i < 8; ++i) { c = sv[i] * c + xv[i]; P *= sv[i]; }
    }
    cend[(size_t)bi * 512 + k] = c;
    if (k == 0) Pq[bi] = P;
}

__global__ __launch_bounds__(512) void count_phaseB(const float* __restrict__ cend,
                                                    const float* __restrict__ Pq,
                                                    float* __restrict__ cin)
{
    int k = threadIdx.x, b = blockIdx.x;
    float c = 0.f;
    for (int q = 0; q < 8; ++q) {
        int bi = b * 8 + q;
        cin[(size_t)bi * 512 + k] = c;
        c = Pq[bi] * c + cend[(size_t)bi * 512 + k];
    }
}

__global__ __launch_bounds__(512) void count_phaseC(const float* __restrict__ x,
                                                    const float* __restrict__ s,
                                                    const float* __restrict__ cin,
                                                    u16* __restrict__ xbf,
                                                    u16* __restrict__ clog)
{
    int k = threadIdx.x, bi = blockIdx.x;
    int b = bi >> 3, qc = bi & 7;
    size_t base = ((size_t)b * 1024 + qc * 128) * 512;
    const float* xb = x + base;
    const float* sb = s + b * 1024 + qc * 128;
    u16* xo = xbf + base;
    u16* co = clog + base;
    float c = cin[(size_t)bi * 512 + k];
    for (int t0 = 0; t0 < 128; t0 += 8) {
        float xv[8], sv[8];
        #pragma unroll
        for (int i = 0; i < 8; ++i) {
            xv[i] = xb[(size_t)(t0 + i) * 512 + k];
            sv[i] = sb[t0 + i];
        }
        #pragma unroll
        for (int i = 0; i < 8; ++i) {
            c = sv[i] * c + xv[i];
            size_t idx = (size_t)(t0 + i) * 512 + k;
            xo[idx] = f2bf(xv[i]);
            co[idx] = f2bf(log1pf(c));
        }
    }
}

// ---------------------------------------------------------------------------
// xc[:,256] = exp(-(delta*Wd+bd)); xc[:,257:288] = 0
// ---------------------------------------------------------------------------
__global__ __launch_bounds__(256) void fill_xc(const float* __restrict__ delta,
                                               const float* __restrict__ Wd,
                                               const float* __restrict__ bd,
                                               u16* __restrict__ xc)
{
    int i = blockIdx.x * 256 + threadIdx.x;   // 65536*32
    int row = i >> 5, cc = i & 31;
    float v = 0.f;
    if (cc == 0) v = __expf(-(delta[row] * Wd[0] + bd[0]));
    xc[(size_t)row * 288 + 256 + cc] = f2bf(v);
}

// ---------------------------------------------------------------------------
// Generic 128x128-tile bf16 MFMA GEMM: C[row, colofs+col] = A@B + bias.
// ---------------------------------------------------------------------------
template <int EPI>
__global__ __launch_bounds__(256) void gemm128(const u16* __restrict__ A,
                                               const u16* __restrict__ BT,
                                               const float* __restrict__ bias,
                                               u16* __restrict__ C,
                                               int K, int ldc, int colofs)
{
    __shared__ u16 Alds[128 * 40];
    __shared__ u16 Blds[128 * 40];
    int tid = threadIdx.x;
    int m0 = blockIdx.x * 128, n0 = blockIdx.y * 128;
    int lane = tid & 63, w = tid >> 6, quad = lane >> 4, m16 = lane & 15;
    int wm = w & 1, wn = w >> 1;
    f4v acc[4][4];
    #pragma unroll
    for (int i = 0; i < 4; ++i)
        #pragma unroll
        for (int j = 0; j < 4; ++j) acc[i][j] = (f4v){0.f, 0.f, 0.f, 0.f};

    for (int k0 = 0; k0 < K; k0 += 32) {
        #pragma unroll
        for (int p = 0; p < 2; ++p) {
            int e = (p * 256 + tid) * 8;
            int r = e >> 5, cc = e & 31;
            *(uint4*)&Alds[r * 40 + cc] =
                *(const uint4*)&A[(size_t)(m0 + r) * K + k0 + cc];
            *(uint4*)&Blds[r * 40 + cc] =
                *(const uint4*)&BT[(size_t)(n0 + r) * K + k0 + cc];
        }
        __syncthreads();
        s8v af[4], bf[4];
        #pragma unroll
        for (int i = 0; i < 4; ++i)
            af[i] = *(const s8v*)&Alds[(wm * 64 + i * 16 + m16) * 40 + quad * 8];
        #pragma unroll
        for (int i = 0; i < 4; ++i)
            bf[i] = *(const s8v*)&Blds[(wn * 64 + i * 16 + m16) * 40 + quad * 8];
        #pragma unroll
        for (int i = 0; i < 4; ++i)
            #pragma unroll
            for (int nj = 0; nj < 4; ++nj)
                acc[i][nj] = __builtin_amdgcn_mfma_f32_16x16x32_bf16(
                    af[i], bf[nj], acc[i][nj], 0, 0, 0);
        __syncthreads();
    }
    #pragma unroll
    for (int nj = 0; nj < 4; ++nj) {
        int col = n0 + wn * 64 + nj * 16 + m16;
        float bv = bias[col];
        #pragma unroll
        for (int i = 0; i < 4; ++i)
            #pragma unroll
            for (int r = 0; r < 4; ++r) {
                int row = m0 + wm * 64 + i * 16 + quad * 4 + r;
                float v = acc[i][nj][r] + bv;
                C[(size_t)row * ldc + colofs + col] = (EPI == 0) ? f2bf(v) : f2h(v);
            }
    }
}

// ---------------------------------------------------------------------------
// LSTM over T=1024 via broadcast-A MFMA GEMV. One block per batch, 256 thr.
// Wave w owns h-cols [w*64, w*64+64); per cg (16-col cluster) the 4 gate
// z-rows come out of acc[g][0] on every lane; lane keeps only cg == quad
// (its own column tid) via cndmask select -> gates computed once per lane.
// Ul resident as B-frags: kt 0..5 in regs (384/wave), kt 6..7 in LDS.
// pre[t] prefetched one step ahead into registers (4 coalesced u16 loads).
// Per-step barrier is raw s_waitcnt lgkmcnt(0) + s_barrier: global loads
// (pre prefetch) and stores (hout) stay in flight across it -- no vmcnt
// drain on the critical path.
// ---------------------------------------------------------------------------
__global__ __launch_bounds__(256, 1) void lstm_kernel(const f16* __restrict__ pre,
                                                      const u16* __restrict__ ulB,
                                                      u16* __restrict__ hout)
{
    extern __shared__ char smem[];
    f16x8* wlds = (f16x8*)smem;                         // [128][64] frags kt 6,7
    f16* hl = (f16*)(smem + LSTM_WLDS);                 // [2][256] h state
    const int tid = threadIdx.x, b = blockIdx.x;
    const int w = tid >> 6, lane = tid & 63, quad = lane >> 4;

    const f16x8* ub = (const f16x8*)ulB;
    // register-resident weights: kt 0..5 for this wave's 16 (cg,g) tiles
    f16x8 wr[4][4][6];
    #pragma unroll
    for (int cg = 0; cg < 4; ++cg)
        #pragma unroll
        for (int g = 0; g < 4; ++g)
            #pragma unroll
            for (int kt = 0; kt < 6; ++kt)
                wr[cg][g][kt] =
                    ub[(size_t)(((w * 16 + cg * 4 + g) * 6 + kt) * 64 + lane)];
    // stage LDS-resident weights (own wave's 32 frags; only read by this wave)
    {
        const f16x8* ubl = ub + 384 * 64;
        #pragma unroll
        for (int i2 = 0; i2 < 32; ++i2)
            wlds[(w * 32 + i2) * 64 + lane] = ubl[(size_t)((w * 32 + i2) * 64 + lane)];
    }
    const f16* prep_ = pre + (size_t)b * 1024 * 1024;
    const f16* pcol = prep_ + tid;          // lane's column stream
    u16* ho = hout + (size_t)b * 1024 * 256;
    hl[tid] = (f16)0.f;
    float c = 0.f;
    f16 pcur[4];
    #pragma unroll
    for (int g = 0; g < 4; ++g) pcur[g] = pcol[g * 256];
    __syncthreads();

    const f4v z4 = {0.f, 0.f, 0.f, 0.f};
    const int wldsbase = w * 32 * 64 + lane;
    #pragma unroll 1
    for (int t = 0; t < 1024; ++t) {
        // h k-slices for this quad (broadcast LDS reads) -- issue first
        const int cb = (t & 1) * 256 + quad * 8;
        f16x8 av[8];
        #pragma unroll
        for (int kt = 0; kt < 8; ++kt)
            av[kt] = *(const f16x8*)&hl[cb + kt * 32];
        // prefetch pre[t+1] for this lane (in flight across the barrier)
        int t1 = (t < 1023) ? (t + 1) : 1023;
        f16 pnext[4];
        #pragma unroll
        for (int g = 0; g < 4; ++g) pnext[g] = pcol[(size_t)t1 * 1024 + g * 256];

        float zq[4] = {0.f, 0.f, 0.f, 0.f};
        #pragma unroll
        for (int cg = 0; cg < 4; ++cg) {
            f16x8 wl[4][2];
            #pragma unroll
            for (int g = 0; g < 4; ++g)
                #pragma unroll
                for (int k6 = 0; k6 < 2; ++k6)
                    wl[g][k6] = wlds[wldsbase + ((cg * 4 + g) * 2 + k6) * 64];
            f4v acc[4];
            #pragma unroll
            for (int g = 0; g < 4; ++g)
                acc[g] = __builtin_amdgcn_mfma_f32_16x16x32_f16(
                    av[0], wr[cg][g][0], z4, 0, 0, 0);
            #pragma unroll
            for (int kt = 1; kt < 6; ++kt)
                #pragma unroll
                for (int g = 0; g < 4; ++g)
                    acc[g] = __builtin_amdgcn_mfma_f32_16x16x32_f16(
                        av[kt], wr[cg][g][kt], acc[g], 0, 0, 0);
            #pragma unroll
            for (int k6 = 0; k6 < 2; ++k6)
                #pragma unroll
                for (int g = 0; g < 4; ++g)
                    acc[g] = __builtin_amdgcn_mfma_f32_16x16x32_f16(
                        av[6 + k6], wl[g][k6], acc[g], 0, 0, 0);
            // keep only this lane's own column cluster (cg == quad)
            #pragma unroll
            for (int g = 0; g < 4; ++g)
                zq[g] = (quad == cg) ? acc[g][0] : zq[g];
        }
        // gates, once per lane (column = tid)
        float z0 = zq[0] + (float)pcur[0];
        float z1 = zq[1] + (float)pcur[1];
        float z2 = zq[2] + (float)pcur[2];
        float z3 = zq[3] + (float)pcur[3];
        float ig = sigm(z0), fg = sigm(z1);
        float gg = fast_tanh(z2), og = sigm(z3);
        c = fg * c + ig * gg;
        float hs = og * fast_tanh(c);
        hl[((t + 1) & 1) * 256 + tid] = (f16)hs;
        ho[(size_t)t * 256 + tid] = f2bf(hs);       // fire-and-forget
        #pragma unroll
        for (int g = 0; g < 4; ++g) pcur[g] = pnext[g];
        // raw barrier: drain LDS only; vmem ops continue across
        asm volatile("s_waitcnt lgkmcnt(0)\n\ts_barrier" ::: "memory");
    }
}

// ---------------------------------------------------------------------------
// out[row] = sum_n sigmoid(h[row]@Wo[:,n] + bo[n]) * q[row,n]
// ---------------------------------------------------------------------------
__global__ __launch_bounds__(256) void gemm_out(const u16* __restrict__ H,
                                                const u16* __restrict__ woT,
                                                const float* __restrict__ bo,
                                                const float* __restrict__ q,
                                                float* __restrict__ out)
{
    __shared__ u16 Alds[64 * 40];
    __shared__ u16 Blds[256 * 40];
    __shared__ float red[64][4];
    int tid = threadIdx.x;
    int m0 = blockIdx.x * 64;
    int lane = tid & 63, w = tid >> 6, quad = lane >> 4, m16 = lane & 15;
    f4v acc[4][4];
    #pragma unroll
    for (int i = 0; i < 4; ++i)
        #pragma unroll
        for (int j = 0; j < 4; ++j) acc[i][j] = (f4v){0.f, 0.f, 0.f, 0.f};

    for (int k0 = 0; k0 < 256; k0 += 32) {
        {
            int e = tid * 8;
            int r = e >> 5, cc = e & 31;
            *(uint4*)&Alds[r * 40 + cc] =
                *(const uint4*)&H[(size_t)(m0 + r) * 256 + k0 + cc];
        }
        #pragma unroll
        for (int p = 0; p < 4; ++p) {
            int e = (p * 256 + tid) * 8;
            int r = e >> 5, cc = e & 31;
            *(uint4*)&Blds[r * 40 + cc] =
                *(const uint4*)&woT[(size_t)r * 256 + k0 + cc];
        }
        __syncthreads();
        s8v af[4], bf[4];
        #pragma unroll
        for (int i = 0; i < 4; ++i)
            af[i] = *(const s8v*)&Alds[(i * 16 + m16) * 40 + quad * 8];
        #pragma unroll
        for (int i = 0; i < 4; ++i)
            bf[i] = *(const s8v*)&Blds[(w * 64 + i * 16 + m16) * 40 + quad * 8];
        #pragma unroll
        for (int i = 0; i < 4; ++i)
            #pragma unroll
            for (int nj = 0; nj < 4; ++nj)
                acc[i][nj] = __builtin_amdgcn_mfma_f32_16x16x32_bf16(
                    af[i], bf[nj], acc[i][nj], 0, 0, 0);
        __syncthreads();
    }
    float rsum[4][4];
    #pragma unroll
    for (int i = 0; i < 4; ++i)
        #pragma unroll
        for (int r = 0; r < 4; ++r) rsum[i][r] = 0.f;
    #pragma unroll
    for (int nj = 0; nj < 4; ++nj) {
        int col = w * 64 + nj * 16 + m16;
        float bv = bo[col];
        #pragma unroll
        for (int i = 0; i < 4; ++i)
            #pragma unroll
            for (int r = 0; r < 4; ++r) {
                int row = m0 + i * 16 + quad * 4 + r;
                float v = sigm(acc[i][nj][r] + bv);
                rsum[i][r] += v * q[(size_t)row * 256 + col];
            }
    }
    #pragma unroll
    for (int d = 1; d <= 8; d <<= 1)
        #pragma unroll
        for (int i = 0; i < 4; ++i)
            #pragma unroll
            for (int r = 0; r < 4; ++r) rsum[i][r] += __shfl_xor(rsum[i][r], d);
    if (m16 == 0) {
        #pragma unroll
        for (int i = 0; i < 4; ++i)
            #pragma unroll
            for (int r = 0; r < 4; ++r)
                red[i * 16 + quad * 4 + r][w] = rsum[i][r];
    }
    __syncthreads();
    if (tid < 64)
        out[m0 + tid] = red[tid][0] + red[tid][1] + red[tid][2] + red[tid][3];
}

// ---------------------------------------------------------------------------
extern "C" void kernel_launch(void* const* d_in, const int* in_sizes, int n_in,
                              void* d_out, int out_size, void* d_ws, size_t ws_size,
                              hipStream_t stream)
{
    (void)in_sizes; (void)n_in; (void)out_size; (void)ws_size;
    const float* x     = (const float*)d_in[0];
    const float* delta = (const float*)d_in[1];
    const float* q     = (const float*)d_in[2];
    const float* Wx    = (const float*)d_in[3];
    const float* bx    = (const float*)d_in[4];
    const float* Wc    = (const float*)d_in[5];
    const float* bc    = (const float*)d_in[6];
    const float* Wd    = (const float*)d_in[7];
    const float* bd    = (const float*)d_in[8];
    const float* Wl    = (const float*)d_in[9];
    const float* Ul    = (const float*)d_in[10];
    const float* bl    = (const float*)d_in[11];
    const float* Wo    = (const float*)d_in[12];
    const float* bo    = (const float*)d_in[13];

    char* ws = (char*)d_ws;
    float* s_buf = (float*)(ws + 0);            // 256 KB
    u16* ulB     = (u16*)(ws + 262144);         // 512 KB (B-frag layout f16)
    u16* wxT     = (u16*)(ws + 786432);         // 128 KB
    u16* wcT     = (u16*)(ws + 917504);         // 128 KB
    u16* wlT     = (u16*)(ws + 1048576);        // 576 KB
    u16* woT     = (u16*)(ws + 1638400);        // 128 KB
    u16* xc      = (u16*)(ws + 1769472);        // 36 MB  [65536 x 288] bf16
    u16* hbuf    = (u16*)(ws + 39518208);       // 32 MB  [65536 x 256] bf16
    u16* xbf     = (u16*)(ws + 73072640);       // 64 MB  bf16 copy of x
    u16* clog    = (u16*)(ws + 140181504);      // 64 MB  log1p(counts) bf16
    f16* pre     = (f16*)(ws + 73072640);       // 128 MB f16, aliases xbf+clog
    // count-scan scratch lives in the (not yet used) hbuf region
    float* cend  = (float*)hbuf;                // 1 MB
    float* cin   = (float*)(ws + 39518208 + (1 << 20));   // 1 MB
    float* Pq    = (float*)(ws + 39518208 + (2 << 20));   // 2 KB

    // allow >64KB dynamic LDS for the LSTM kernel (gfx950: 160 KB/WG)
    hipFuncSetAttribute((const void*)lstm_kernel,
                        hipFuncAttributeMaxDynamicSharedMemorySize, LSTM_SMEM);

    prep_kernel<<<2048, 256, 0, stream>>>(Wx, Wc, Wl, Wo, Ul, wxT, wcT, wlT, woT, ulB);
    row_sums<<<16384, 256, 0, stream>>>((const float4*)x, s_buf);
    count_phaseA<<<512, 512, 0, stream>>>(x, s_buf, cend, Pq);
    count_phaseB<<<64, 512, 0, stream>>>(cend, Pq, cin);
    count_phaseC<<<512, 512, 0, stream>>>(x, s_buf, cin, xbf, clog);
    fill_xc<<<8192, 256, 0, stream>>>(delta, Wd, bd, xc);
    gemm128<0><<<dim3(512, 1), 256, 0, stream>>>(xbf, wxT, bx, xc, 512, 288, 0);
    gemm128<0><<<dim3(512, 1), 256, 0, stream>>>(clog, wcT, bc, xc, 512, 288, 128);
    gemm128<1><<<dim3(512, 8), 256, 0, stream>>>(xc, wlT, bl, (u16*)pre, 288, 1024, 0);
    lstm_kernel<<<64, 256, LSTM_SMEM, stream>>>(pre, ulB, hbuf);
    gemm_out<<<1024, 256, 0, stream>>>(hbuf, woT, bo, q, (float*)d_out);
}

// Round 3
// 1995.099 us; speedup vs baseline: 1.7606x; 1.4360x over previous
//
#include <hip/hip_runtime.h>
#include <hip/hip_bf16.h>

typedef unsigned short u16;
typedef _Float16 f16;
typedef _Float16 f16x8 __attribute__((ext_vector_type(8)));
typedef short s8v __attribute__((ext_vector_type(8)));
typedef float f4v __attribute__((ext_vector_type(4)));

// LSTM LDS layout: 128 weight frags (kt 6,7) + h state double buffer
#define LSTM_WLDS 131072                 // 128 frags x 64 lanes x 16 B
#define LSTM_HLDS 1024                   // hl[2][256] f16
#define LSTM_SMEM (LSTM_WLDS + LSTM_HLDS)   // 132096

__device__ __forceinline__ u16 f2bf(float f) {
    union { float f; unsigned u; } v; v.f = f;
    unsigned r = v.u + 0x7FFF + ((v.u >> 16) & 1);
    return (u16)(r >> 16);
}
__device__ __forceinline__ u16 f2h(float f) {
    f16 h = (f16)f;
    union { f16 h; u16 u; } v; v.h = h;
    return v.u;
}
__device__ __forceinline__ float sigm(float x) { return 1.f / (1.f + __expf(-x)); }
__device__ __forceinline__ float fast_tanh(float x) {
    float ax = fabsf(x);
    float e = __expf(2.f * ax);
    float r = 1.f - 2.f / (e + 1.f);   // overflow-safe: e=inf -> r=1
    return copysignf(r, x);
}

// Inline-asm MFMA with explicit operand classes (gfx950: A/B may be AGPR).
// Chains only reuse D as SrcC (0 wait states required). All volatile: the
// source order (kt-major, g-inner) IS the schedule for the 4 chains.
#define MFMA_INIT(D, A, B, C) \
    asm volatile("v_mfma_f32_16x16x32_f16 %0, %1, %2, %3" \
                 : "=v"(D) : "v"(A), "a"(B), "v"(C))
#define MFMA_AG(D, A, B) \
    asm volatile("v_mfma_f32_16x16x32_f16 %0, %1, %2, %0" \
                 : "+v"(D) : "v"(A), "a"(B))
#define MFMA_VG(D, A, B) \
    asm volatile("v_mfma_f32_16x16x32_f16 %0, %1, %2, %0" \
                 : "+v"(D) : "v"(A), "v"(B))

// ---------------------------------------------------------------------------
// Weight prep: transposes to [N][K] bf16 for MFMA B-operand for the GEMMs,
// and packs Ul into f16 MFMA B-fragment layout for the LSTM:
//   512 frags, frag F: tile = (w,cg,g), kt;  lane l holds 8 f16:
//     B[k][n], k = kt*32 + (l>>4)*8 + j,  n = g*256 + w*64 + cg*16 + (l&15)
//   F < 384: register region, F = tile*6 + kt (kt 0..5)
//   F >=384: LDS region,      F = 384 + tile*2 + (kt-6)
// ---------------------------------------------------------------------------
__global__ __launch_bounds__(256) void prep_kernel(
    const float* __restrict__ Wx, const float* __restrict__ Wc,
    const float* __restrict__ Wl, const float* __restrict__ Wo,
    const float* __restrict__ Ul,
    u16* __restrict__ wxT, u16* __restrict__ wcT, u16* __restrict__ wlT,
    u16* __restrict__ woT, u16* __restrict__ ulB)
{
    int i = blockIdx.x * 256 + threadIdx.x;
    if (i < 65536) {                    // WxT[n][k] : 128x512
        int n = i >> 9, k = i & 511;
        wxT[i] = f2bf(Wx[k * 128 + n]);
    } else if (i < 131072) {            // WcT
        int t = i - 65536;
        int n = t >> 9, k = t & 511;
        wcT[t] = f2bf(Wc[k * 128 + n]);
    } else if (i < 425984) {            // WlT[n][k] : 1024x288 (K padded 257->288)
        int t = i - 131072;
        int n = t / 288, k = t % 288;
        wlT[t] = (k < 257) ? f2bf(Wl[k * 1024 + n]) : (u16)0;
    } else if (i < 491520) {            // WoT[n][k] : 256x256
        int t = i - 425984;
        int n = t >> 8, k = t & 255;
        woT[t] = f2bf(Wo[k * 256 + n]);
    } else {                            // ulB: 512 B-frags f16, i in [491520, 524288)
        int e = i - 491520;             // [0, 32768): one f16x8 element each
        int F = e >> 6, lane = e & 63;
        int m16 = lane & 15, quad = lane >> 4;
        int tile, kt;
        if (F < 384) { tile = F / 6; kt = F - tile * 6; }
        else { int L = F - 384; tile = L >> 1; kt = 6 + (L & 1); }
        int wv = tile >> 4, cg = (tile >> 2) & 3, g = tile & 3;
        int n = g * 256 + wv * 64 + cg * 16 + m16;
        int k0 = kt * 32 + quad * 8;
        u16* o = ulB + (size_t)e * 8;
        #pragma unroll
        for (int jj = 0; jj < 8; ++jj)
            o[jj] = f2h(Ul[(size_t)(k0 + jj) * 1024 + n]);
    }
}

// ---------------------------------------------------------------------------
// s[b,t] = sum_k x[b,t,k]   (one wave per row)
// ---------------------------------------------------------------------------
__global__ __launch_bounds__(256) void row_sums(const float4* __restrict__ x4,
                                                float* __restrict__ s)
{
    int w = threadIdx.x >> 6, lane = threadIdx.x & 63;
    size_t row = (size_t)blockIdx.x * 4 + w;
    const float4* r = x4 + row * 128;
    float4 a = r[lane], b = r[64 + lane];
    float sum = a.x + a.y + a.z + a.w + b.x + b.y + b.z + b.w;
    #pragma unroll
    for (int d = 32; d >= 1; d >>= 1) sum += __shfl_xor(sum, d);
    if (lane == 0) s[row] = sum;
}

// ---------------------------------------------------------------------------
// Count recurrence, 3-phase chunked (8 chunks of 128 steps per batch):
// A: per-chunk zero-init scan -> cend, P=prod(s).  B: combine chunk heads.
// C: re-scan with true c_in, write bf16 x and log1p(count).
// ---------------------------------------------------------------------------
__global__ __launch_bounds__(512) void count_phaseA(const float* __restrict__ x,
                                                    const float* __restrict__ s,
                                                    float* __restrict__ cend,
                                                    float* __restrict__ Pq)
{
    int k = threadIdx.x, bi = blockIdx.x;
    int b = bi >> 3, qc = bi & 7;
    const float* xb = x + ((size_t)b * 1024 + qc * 128) * 512;
    const float* sb = s + b * 1024 + qc * 128;
    float c = 0.f, P = 1.f;
    for (int t0 = 0; t0 < 128; t0 += 8) {
        float xv[8], sv[8];
        #pragma unroll
        for (int i = 0; i < 8; ++i) {
            xv[i] = xb[(size_t)(t0 + i) * 512 + k];
            sv[i] = sb[t0 + i];
        }
        #pragma unroll
        for (int i = 0; i < 8; ++i) { c = sv[i] * c + xv[i]; P *= sv[i]; }
    }
    cend[(size_t)bi * 512 + k] = c;
    if (k == 0) Pq[bi] = P;
}

__global__ __launch_bounds__(512) void count_phaseB(const float* __restrict__ cend,
                                                    const float* __restrict__ Pq,
                                                    float* __restrict__ cin)
{
    int k = threadIdx.x, b = blockIdx.x;
    float c = 0.f;
    for (int q = 0; q < 8; ++q) {
        int bi = b * 8 + q;
        cin[(size_t)bi * 512 + k] = c;
        c = Pq[bi] * c + cend[(size_t)bi * 512 + k];
    }
}

__global__ __launch_bounds__(512) void count_phaseC(const float* __restrict__ x,
                                                    const float* __restrict__ s,
                                                    const float* __restrict__ cin,
                                                    u16* __restrict__ xbf,
                                                    u16* __restrict__ clog)
{
    int k = threadIdx.x, bi = blockIdx.x;
    int b = bi >> 3, qc = bi & 7;
    size_t base = ((size_t)b * 1024 + qc * 128) * 512;
    const float* xb = x + base;
    const float* sb = s + b * 1024 + qc * 128;
    u16* xo = xbf + base;
    u16* co = clog + base;
    float c = cin[(size_t)bi * 512 + k];
    for (int t0 = 0; t0 < 128; t0 += 8) {
        float xv[8], sv[8];
        #pragma unroll
        for (int i = 0; i < 8; ++i) {
            xv[i] = xb[(size_t)(t0 + i) * 512 + k];
            sv[i] = sb[t0 + i];
        }
        #pragma unroll
        for (int i = 0; i < 8; ++i) {
            c = sv[i] * c + xv[i];
            size_t idx = (size_t)(t0 + i) * 512 + k;
            xo[idx] = f2bf(xv[i]);
            co[idx] = f2bf(log1pf(c));
        }
    }
}

// ---------------------------------------------------------------------------
// xc[:,256] = exp(-(delta*Wd+bd)); xc[:,257:288] = 0
// ---------------------------------------------------------------------------
__global__ __launch_bounds__(256) void fill_xc(const float* __restrict__ delta,
                                               const float* __restrict__ Wd,
                                               const float* __restrict__ bd,
                                               u16* __restrict__ xc)
{
    int i = blockIdx.x * 256 + threadIdx.x;   // 65536*32
    int row = i >> 5, cc = i & 31;
    float v = 0.f;
    if (cc == 0) v = __expf(-(delta[row] * Wd[0] + bd[0]));
    xc[(size_t)row * 288 + 256 + cc] = f2bf(v);
}

// ---------------------------------------------------------------------------
// Generic 128x128-tile bf16 MFMA GEMM: C[row, colofs+col] = A@B + bias.
// ---------------------------------------------------------------------------
template <int EPI>
__global__ __launch_bounds__(256) void gemm128(const u16* __restrict__ A,
                                               const u16* __restrict__ BT,
                                               const float* __restrict__ bias,
                                               u16* __restrict__ C,
                                               int K, int ldc, int colofs)
{
    __shared__ u16 Alds[128 * 40];
    __shared__ u16 Blds[128 * 40];
    int tid = threadIdx.x;
    int m0 = blockIdx.x * 128, n0 = blockIdx.y * 128;
    int lane = tid & 63, w = tid >> 6, quad = lane >> 4, m16 = lane & 15;
    int wm = w & 1, wn = w >> 1;
    f4v acc[4][4];
    #pragma unroll
    for (int i = 0; i < 4; ++i)
        #pragma unroll
        for (int j = 0; j < 4; ++j) acc[i][j] = (f4v){0.f, 0.f, 0.f, 0.f};

    for (int k0 = 0; k0 < K; k0 += 32) {
        #pragma unroll
        for (int p = 0; p < 2; ++p) {
            int e = (p * 256 + tid) * 8;
            int r = e >> 5, cc = e & 31;
            *(uint4*)&Alds[r * 40 + cc] =
                *(const uint4*)&A[(size_t)(m0 + r) * K + k0 + cc];
            *(uint4*)&Blds[r * 40 + cc] =
                *(const uint4*)&BT[(size_t)(n0 + r) * K + k0 + cc];
        }
        __syncthreads();
        s8v af[4], bf[4];
        #pragma unroll
        for (int i = 0; i < 4; ++i)
            af[i] = *(const s8v*)&Alds[(wm * 64 + i * 16 + m16) * 40 + quad * 8];
        #pragma unroll
        for (int i = 0; i < 4; ++i)
            bf[i] = *(const s8v*)&Blds[(wn * 64 + i * 16 + m16) * 40 + quad * 8];
        #pragma unroll
        for (int i = 0; i < 4; ++i)
            #pragma unroll
            for (int nj = 0; nj < 4; ++nj)
                acc[i][nj] = __builtin_amdgcn_mfma_f32_16x16x32_bf16(
                    af[i], bf[nj], acc[i][nj], 0, 0, 0);
        __syncthreads();
    }
    #pragma unroll
    for (int nj = 0; nj < 4; ++nj) {
        int col = n0 + wn * 64 + nj * 16 + m16;
        float bv = bias[col];
        #pragma unroll
        for (int i = 0; i < 4; ++i)
            #pragma unroll
            for (int r = 0; r < 4; ++r) {
                int row = m0 + wm * 64 + i * 16 + quad * 4 + r;
                float v = acc[i][nj][r] + bv;
                C[(size_t)row * ldc + colofs + col] = (EPI == 0) ? f2bf(v) : f2h(v);
            }
    }
}

// ---------------------------------------------------------------------------
// LSTM over T=1024 via broadcast-A MFMA GEMV. One block per batch, 256 thr.
// Wave w owns h-cols [w*64, w*64+64); per cg (16-col cluster) the 4 gate
// z-rows come out of acc[g][0] on every lane; lane keeps only cg == quad.
// Weight residency (per wave, 128 frags):
//   kt 0..3 -> 64 frags pinned in AGPRs (class-forced, read directly by
//              asm MFMA "a" operands; zero per-step moves)
//   kt 4..5 -> 32 frags in arch VGPRs
//   kt 6..7 -> 32 frags streamed from LDS, single 8-frag buffer per cg;
//              the 24 register-operand MFMAs hide the LDS latency.
// Per-step barrier: s_waitcnt lgkmcnt(0) + s_barrier only (vmem in flight).
// ---------------------------------------------------------------------------
__global__ __launch_bounds__(256, 1) void lstm_kernel(const f16* __restrict__ pre,
                                                      const u16* __restrict__ ulB,
                                                      u16* __restrict__ hout)
{
    extern __shared__ char smem[];
    f16x8* wlds = (f16x8*)smem;                         // [128][64] frags kt 6,7
    f16* hl = (f16*)(smem + LSTM_WLDS);                 // [2][256] h state
    const int tid = threadIdx.x, b = blockIdx.x;
    const int w = tid >> 6, lane = tid & 63, quad = lane >> 4;

    const f16x8* ub = (const f16x8*)ulB;
    // kt 0..3 -> AGPR-pinned (64 frags = 256 AGPRs)
    f16x8 wa[4][4][4];
    #pragma unroll
    for (int cg = 0; cg < 4; ++cg)
        #pragma unroll
        for (int g = 0; g < 4; ++g)
            #pragma unroll
            for (int kt = 0; kt < 4; ++kt) {
                f16x8 tmp = ub[(size_t)(((w * 16 + cg * 4 + g) * 6 + kt) * 64 + lane)];
                asm("" : "=a"(wa[cg][g][kt]) : "0"(tmp));   // class-force, 1-time copy
            }
    // kt 4..5 -> arch VGPR (32 frags = 128 VGPRs)
    f16x8 wv[4][4][2];
    #pragma unroll
    for (int cg = 0; cg < 4; ++cg)
        #pragma unroll
        for (int g = 0; g < 4; ++g)
            #pragma unroll
            for (int kt = 0; kt < 2; ++kt)
                wv[cg][g][kt] =
                    ub[(size_t)(((w * 16 + cg * 4 + g) * 6 + 4 + kt) * 64 + lane)];
    // stage kt6,7 frags to LDS (own wave's 32 frags)
    {
        const f16x8* ubl = ub + 384 * 64;
        #pragma unroll
        for (int i2 = 0; i2 < 32; ++i2)
            wlds[(w * 32 + i2) * 64 + lane] = ubl[(size_t)((w * 32 + i2) * 64 + lane)];
    }
    const f16* prep_ = pre + (size_t)b * 1024 * 1024;
    const f16* pcol = prep_ + tid;          // lane's column stream
    u16* ho = hout + (size_t)b * 1024 * 256;
    hl[tid] = (f16)0.f;
    float c = 0.f;
    f16 pcur[4];
    #pragma unroll
    for (int g = 0; g < 4; ++g) pcur[g] = pcol[g * 256];
    f4v z4 = {0.f, 0.f, 0.f, 0.f};
    __syncthreads();

    const int wldsbase = w * 32 * 64 + lane;
    #pragma unroll 1
    for (int t = 0; t < 1024; ++t) {
        // h k-slices for this quad (broadcast LDS reads)
        const int cb = (t & 1) * 256 + quad * 8;
        f16x8 av[8];
        #pragma unroll
        for (int kt = 0; kt < 8; ++kt)
            av[kt] = *(const f16x8*)&hl[cb + kt * 32];
        // prefetch pre[t+1] (stays in flight across the barrier)
        int t1 = (t < 1023) ? (t + 1) : 1023;
        f16 pnext[4];
        #pragma unroll
        for (int g = 0; g < 4; ++g) pnext[g] = pcol[(size_t)t1 * 1024 + g * 256];

        float zq0 = 0.f, zq1 = 0.f, zq2 = 0.f, zq3 = 0.f;
        #pragma unroll
        for (int cg = 0; cg < 4; ++cg) {
            // issue this cg's 8 LDS weight reads; the 24 reg-MFMAs below
            // cover their latency (precise lgkmcnt(N) from the compiler)
            f16x8 wlb[8];
            #pragma unroll
            for (int g = 0; g < 4; ++g) {
                wlb[g * 2 + 0] = wlds[wldsbase + ((cg * 4 + g) * 2 + 0) * 64];
                wlb[g * 2 + 1] = wlds[wldsbase + ((cg * 4 + g) * 2 + 1) * 64];
            }
            f4v A0, A1, A2, A3;
            MFMA_INIT(A0, av[0], wa[cg][0][0], z4);
            MFMA_INIT(A1, av[0], wa[cg][1][0], z4);
            MFMA_INIT(A2, av[0], wa[cg][2][0], z4);
            MFMA_INIT(A3, av[0], wa[cg][3][0], z4);
            #pragma unroll
            for (int kt = 1; kt < 4; ++kt) {
                MFMA_AG(A0, av[kt], wa[cg][0][kt]);
                MFMA_AG(A1, av[kt], wa[cg][1][kt]);
                MFMA_AG(A2, av[kt], wa[cg][2][kt]);
                MFMA_AG(A3, av[kt], wa[cg][3][kt]);
            }
            #pragma unroll
            for (int kt = 0; kt < 2; ++kt) {
                MFMA_VG(A0, av[4 + kt], wv[cg][0][kt]);
                MFMA_VG(A1, av[4 + kt], wv[cg][1][kt]);
                MFMA_VG(A2, av[4 + kt], wv[cg][2][kt]);
                MFMA_VG(A3, av[4 + kt], wv[cg][3][kt]);
            }
            #pragma unroll
            for (int kt = 0; kt < 2; ++kt) {
                MFMA_VG(A0, av[6 + kt], wlb[0 * 2 + kt]);
                MFMA_VG(A1, av[6 + kt], wlb[1 * 2 + kt]);
                MFMA_VG(A2, av[6 + kt], wlb[2 * 2 + kt]);
                MFMA_VG(A3, av[6 + kt], wlb[3 * 2 + kt]);
            }
            // keep dying B-inputs alive past the MFMAs (no D/B overlap)
            asm volatile("" :: "v"(wlb[0]), "v"(wlb[1]), "v"(wlb[2]), "v"(wlb[3]),
                               "v"(wlb[4]), "v"(wlb[5]), "v"(wlb[6]), "v"(wlb[7]));
            // hazard guard: VALU read of MFMA destination
            asm volatile("s_nop 7\n\ts_nop 7");
            zq0 = (quad == cg) ? A0[0] : zq0;
            zq1 = (quad == cg) ? A1[0] : zq1;
            zq2 = (quad == cg) ? A2[0] : zq2;
            zq3 = (quad == cg) ? A3[0] : zq3;
            __builtin_amdgcn_sched_barrier(0);   // cap pressure: no cross-cg hoist
        }
        // gates, once per lane (column = tid)
        float z0 = zq0 + (float)pcur[0];
        float z1 = zq1 + (float)pcur[1];
        float z2 = zq2 + (float)pcur[2];
        float z3 = zq3 + (float)pcur[3];
        float ig = sigm(z0), fg = sigm(z1);
        float gg = fast_tanh(z2), og = sigm(z3);
        c = fg * c + ig * gg;
        float hs = og * fast_tanh(c);
        hl[((t + 1) & 1) * 256 + tid] = (f16)hs;
        ho[(size_t)t * 256 + tid] = f2bf(hs);       // fire-and-forget
        #pragma unroll
        for (int g = 0; g < 4; ++g) pcur[g] = pnext[g];
        // raw barrier: drain LDS only; vmem ops continue across
        asm volatile("s_waitcnt lgkmcnt(0)\n\ts_barrier" ::: "memory");
    }
}

// ---------------------------------------------------------------------------
// out[row] = sum_n sigmoid(h[row]@Wo[:,n] + bo[n]) * q[row,n]
// ---------------------------------------------------------------------------
__global__ __launch_bounds__(256) void gemm_out(const u16* __restrict__ H,
                                                const u16* __restrict__ woT,
                                                const float* __restrict__ bo,
                                                const float* __restrict__ q,
                                                float* __restrict__ out)
{
    __shared__ u16 Alds[64 * 40];
    __shared__ u16 Blds[256 * 40];
    __shared__ float red[64][4];
    int tid = threadIdx.x;
    int m0 = blockIdx.x * 64;
    int lane = tid & 63, w = tid >> 6, quad = lane >> 4, m16 = lane & 15;
    f4v acc[4][4];
    #pragma unroll
    for (int i = 0; i < 4; ++i)
        #pragma unroll
        for (int j = 0; j < 4; ++j) acc[i][j] = (f4v){0.f, 0.f, 0.f, 0.f};

    for (int k0 = 0; k0 < 256; k0 += 32) {
        {
            int e = tid * 8;
            int r = e >> 5, cc = e & 31;
            *(uint4*)&Alds[r * 40 + cc] =
                *(const uint4*)&H[(size_t)(m0 + r) * 256 + k0 + cc];
        }
        #pragma unroll
        for (int p = 0; p < 4; ++p) {
            int e = (p * 256 + tid) * 8;
            int r = e >> 5, cc = e & 31;
            *(uint4*)&Blds[r * 40 + cc] =
                *(const uint4*)&woT[(size_t)r * 256 + k0 + cc];
        }
        __syncthreads();
        s8v af[4], bf[4];
        #pragma unroll
        for (int i = 0; i < 4; ++i)
            af[i] = *(const s8v*)&Alds[(i * 16 + m16) * 40 + quad * 8];
        #pragma unroll
        for (int i = 0; i < 4; ++i)
            bf[i] = *(const s8v*)&Blds[(w * 64 + i * 16 + m16) * 40 + quad * 8];
        #pragma unroll
        for (int i = 0; i < 4; ++i)
            #pragma unroll
            for (int nj = 0; nj < 4; ++nj)
                acc[i][nj] = __builtin_amdgcn_mfma_f32_16x16x32_bf16(
                    af[i], bf[nj], acc[i][nj], 0, 0, 0);
        __syncthreads();
    }
    float rsum[4][4];
    #pragma unroll
    for (int i = 0; i < 4; ++i)
        #pragma unroll
        for (int r = 0; r < 4; ++r) rsum[i][r] = 0.f;
    #pragma unroll
    for (int nj = 0; nj < 4; ++nj) {
        int col = w * 64 + nj * 16 + m16;
        float bv = bo[col];
        #pragma unroll
        for (int i = 0; i < 4; ++i)
            #pragma unroll
            for (int r = 0; r < 4; ++r) {
                int row = m0 + i * 16 + quad * 4 + r;
                float v = sigm(acc[i][nj][r] + bv);
                rsum[i][r] += v * q[(size_t)row * 256 + col];
            }
    }
    #pragma unroll
    for (int d = 1; d <= 8; d <<= 1)
        #pragma unroll
        for (int i = 0; i < 4; ++i)
            #pragma unroll
            for (int r = 0; r < 4; ++r) rsum[i][r] += __shfl_xor(rsum[i][r], d);
    if (m16 == 0) {
        #pragma unroll
        for (int i = 0; i < 4; ++i)
            #pragma unroll
            for (int r = 0; r < 4; ++r)
                red[i * 16 + quad * 4 + r][w] = rsum[i][r];
    }
    __syncthreads();
    if (tid < 64)
        out[m0 + tid] = red[tid][0] + red[tid][1] + red[tid][2] + red[tid][3];
}

// ---------------------------------------------------------------------------
extern "C" void kernel_launch(void* const* d_in, const int* in_sizes, int n_in,
                              void* d_out, int out_size, void* d_ws, size_t ws_size,
                              hipStream_t stream)
{
    (void)in_sizes; (void)n_in; (void)out_size; (void)ws_size;
    const float* x     = (const float*)d_in[0];
    const float* delta = (const float*)d_in[1];
    const float* q     = (const float*)d_in[2];
    const float* Wx    = (const float*)d_in[3];
    const float* bx    = (const float*)d_in[4];
    const float* Wc    = (const float*)d_in[5];
    const float* bc    = (const float*)d_in[6];
    const float* Wd    = (const float*)d_in[7];
    const float* bd    = (const float*)d_in[8];
    const float* Wl    = (const float*)d_in[9];
    const float* Ul    = (const float*)d_in[10];
    const float* bl    = (const float*)d_in[11];
    const float* Wo    = (const float*)d_in[12];
    const float* bo    = (const float*)d_in[13];

    char* ws = (char*)d_ws;
    float* s_buf = (float*)(ws + 0);            // 256 KB
    u16* ulB     = (u16*)(ws + 262144);         // 512 KB (B-frag layout f16)
    u16* wxT     = (u16*)(ws + 786432);         // 128 KB
    u16* wcT     = (u16*)(ws + 917504);         // 128 KB
    u16* wlT     = (u16*)(ws + 1048576);        // 576 KB
    u16* woT     = (u16*)(ws + 1638400);        // 128 KB
    u16* xc      = (u16*)(ws + 1769472);        // 36 MB  [65536 x 288] bf16
    u16* hbuf    = (u16*)(ws + 39518208);       // 32 MB  [65536 x 256] bf16
    u16* xbf     = (u16*)(ws + 73072640);       // 64 MB  bf16 copy of x
    u16* clog    = (u16*)(ws + 140181504);      // 64 MB  log1p(counts) bf16
    f16* pre     = (f16*)(ws + 73072640);       // 128 MB f16, aliases xbf+clog
    // count-scan scratch lives in the (not yet used) hbuf region
    float* cend  = (float*)hbuf;                // 1 MB
    float* cin   = (float*)(ws + 39518208 + (1 << 20));   // 1 MB
    float* Pq    = (float*)(ws + 39518208 + (2 << 20));   // 2 KB

    // allow >64KB dynamic LDS for the LSTM kernel (gfx950: 160 KB/WG)
    hipFuncSetAttribute((const void*)lstm_kernel,
                        hipFuncAttributeMaxDynamicSharedMemorySize, LSTM_SMEM);

    prep_kernel<<<2048, 256, 0, stream>>>(Wx, Wc, Wl, Wo, Ul, wxT, wcT, wlT, woT, ulB);
    row_sums<<<16384, 256, 0, stream>>>((const float4*)x, s_buf);
    count_phaseA<<<512, 512, 0, stream>>>(x, s_buf, cend, Pq);
    count_phaseB<<<64, 512, 0, stream>>>(cend, Pq, cin);
    count_phaseC<<<512, 512, 0, stream>>>(x, s_buf, cin, xbf, clog);
    fill_xc<<<8192, 256, 0, stream>>>(delta, Wd, bd, xc);
    gemm128<0><<<dim3(512, 1), 256, 0, stream>>>(xbf, wxT, bx, xc, 512, 288, 0);
    gemm128<0><<<dim3(512, 1), 256, 0, stream>>>(clog, wcT, bc, xc, 512, 288, 128);
    gemm128<1><<<dim3(512, 8), 256, 0, stream>>>(xc, wlT, bl, (u16*)pre, 288, 1024, 0);
    lstm_kernel<<<64, 256, LSTM_SMEM, stream>>>(pre, ulB, hbuf);
    gemm_out<<<1024, 256, 0, stream>>>(hbuf, woT, bo, q, (float*)d_out);
}